// Round 10
// baseline (86.996 us; speedup 1.0000x reference)
//
#include <hip/hip_runtime.h>
#include <hip/hip_bf16.h>

#define BB 4
#define NN 64
#define RR 8
#define DD 32
#define HH 96
#define NGROUP (BB*NN*RR)   // 2048
#define LSTR 17             // padded LDS stride (floats) for node repack buffer

// workspace float offsets — all node-side tensors transposed [b*8+r][feat][node]
#define OFF_WR_T  0
#define OFF_WS_T  196608
#define OFF_NER0  393216
#define OFF_NES0  589824
#define OFF_NER1  786432
#define OFF_NES1  983040
#define OFF_ENCT  1179648
#define OFF_AGGT  1376256
#define OFF_PKE   1572864      // edge-side packed weights (hi only), 28416 u32
#define OFF_PKN   1601280      // node-side packed weights (hi+lo), 73728 u32
#define OFF_EE0F  1675008      // ee0 in B-frag bf16 form, 2048*3072 u32

// pk_e u32 offsets (frag = 256 u32; 96x96 mat = 18 frags = 4608)
#define PE_EE0  0
#define PE_W20  4608
#define PE_EE1  9216
#define PE_W21  13824
#define PE_PE   18432
#define PE_PC   23040
#define PE_P2   27648
// pk_n u32 offsets (K=32 mats: 6 frags = 1536/part; K=96 mats: 4608/part; hi then lo)
#define PN_NEW  0
#define PN_WR   3072
#define PN_WS   6144
#define PN_ER0  9216
#define PN_ES0  18432
#define PN_WN12 27648
#define PN_WN3  36864
#define PN_NPW2 46080
#define PN_ER1  55296
#define PN_ES1  64512

typedef __attribute__((ext_vector_type(4))) float f32x4;
typedef __attribute__((ext_vector_type(8))) short bf16x8;
typedef __attribute__((ext_vector_type(4))) unsigned int u32x4;

__device__ __forceinline__ unsigned int pk2(float lo, float hi){
    unsigned short a = __builtin_bit_cast(unsigned short, __float2bfloat16(lo));
    unsigned short b = __builtin_bit_cast(unsigned short, __float2bfloat16(hi));
    return (unsigned)a | ((unsigned)b << 16);
}
// split v into bf16 hi + bf16 lo residual (x ~ hi + lo to ~2^-17 rel)
__device__ __forceinline__ void split2(float v0, float v1, unsigned &h, unsigned &lo){
    float h0 = __bfloat162float(__float2bfloat16(v0));
    float h1 = __bfloat162float(__float2bfloat16(v1));
    h  = pk2(v0, v1);
    lo = pk2(v0 - h0, v1 - h1);
}

#define MFMA16(A,B,C) __builtin_amdgcn_mfma_f32_16x16x32_bf16((A),(B),(C),0,0,0)

// ============ node-kernel helpers: 1 m-tile per wave (6 waves/block) ========
__device__ __forceinline__ void gemm_1m(f32x4 &acc,
    const unsigned* __restrict__ ph, const unsigned* __restrict__ pl,
    int idx, int l, const u32x4 &Bh, const u32x4 &Bl)
{
    bf16x8 bh = __builtin_bit_cast(bf16x8, Bh);
    bf16x8 bl = __builtin_bit_cast(bf16x8, Bl);
    bf16x8 ah = __builtin_bit_cast(bf16x8, *(const u32x4*)&ph[idx*256 + l*4]);
    bf16x8 al = __builtin_bit_cast(bf16x8, *(const u32x4*)&pl[idx*256 + l*4]);
    acc = MFMA16(ah, bh, acc);
    acc = MFMA16(ah, bl, acc);
    acc = MFMA16(al, bh, acc);
}
__device__ __forceinline__ void buildB_lds(const float* sF, int kb, int gq, int cL,
                                           u32x4 &Bh, u32x4 &Bl){
    #pragma unroll
    for (int p=0;p<4;p++){
        int f = 32*kb + 8*gq + 2*p;
        unsigned h, lo;
        split2(sF[f*LSTR + cL], sF[(f+1)*LSTR + cL], h, lo);
        Bh[p] = h; Bl[p] = lo;
    }
}
__device__ __forceinline__ void gemm96_1m(f32x4 &acc,
    const unsigned* __restrict__ ph, const unsigned* __restrict__ pl,
    int w, int l, int gq, int cL, const float* sF)
{
    #pragma unroll
    for (int kb=0;kb<3;kb++){
        u32x4 Bh, Bl;
        buildB_lds(sF, kb, gq, cL, Bh, Bl);
        gemm_1m(acc, ph, pl, w*3+kb, l, Bh, Bl);
    }
}
__device__ __forceinline__ void relu1(f32x4 &acc){
    #pragma unroll
    for (int q=0;q<4;q++) acc[q] = fmaxf(acc[q], 0.f);
}
__device__ __forceinline__ void cinit1(f32x4 &acc, const float* __restrict__ bv, int w, int gq){
    #pragma unroll
    for (int q=0;q<4;q++) acc[q] = bv[16*w+4*gq+q];
}
__device__ __forceinline__ void storeT1(const f32x4 &acc, float* __restrict__ dst,
                                        int w, int gq, int col){
    #pragma unroll
    for (int q=0;q<4;q++) dst[(16*w+4*gq+q)*NN + col] = acc[q];
}
__device__ __forceinline__ void toLds1(const f32x4 &acc, float* sF, int w, int gq, int cL){
    #pragma unroll
    for (int q=0;q<4;q++) sF[(16*w+4*gq+q)*LSTR + cL] = acc[q];
}

// ======== edge-kernel helpers (6 waves/block, 1 m-tile/wave, 4 n-tiles) =====
__device__ __forceinline__ void einit1(f32x4 (&acc)[4], const float* __restrict__ bv,
                                       int m, int gq){
    #pragma unroll
    for (int q=0;q<4;q++){
        float x = bv[16*m+4*gq+q];
        #pragma unroll
        for (int n=0;n<4;n++) acc[n][q] = x;
    }
}
// one kb on one m-tile: acc[n] += A[m][kb] @ Bk[n]
__device__ __forceinline__ void egemm1_kb(f32x4 (&acc)[4],
    const unsigned* __restrict__ Apk, int m, int kb, int l, const u32x4 (&Bk)[4])
{
    bf16x8 a = __builtin_bit_cast(bf16x8, *(const u32x4*)&Apk[((m*3+kb)*64 + l)*4]);
    #pragma unroll
    for (int n=0;n<4;n++){
        bf16x8 bf = __builtin_bit_cast(bf16x8, Bk[n]);
        acc[n] = MFMA16(a, bf, acc[n]);
    }
}
__device__ __forceinline__ void build_ee_kb(u32x4 (&Bk)[4],
    const float* __restrict__ wrt, const float* __restrict__ wst,
    int i, int kb, int gq, int cL)
{
    #pragma unroll
    for (int n=0;n<4;n++)
      #pragma unroll
      for (int p=0;p<4;p++){
        int h = 32*kb + 8*gq + 2*p;
        int j = 16*n + cL;
        float a0 = fmaxf(wrt[h*NN + i]     + wst[h*NN + j],     0.f);
        float a1 = fmaxf(wrt[(h+1)*NN + i] + wst[(h+1)*NN + j], 0.f);
        Bk[n][p] = pk2(a0, a1);
      }
}
__device__ __forceinline__ void load_sB_kb(u32x4 (&Bk)[4], const unsigned* sB, int kb, int l){
    #pragma unroll
    for (int n=0;n<4;n++) Bk[n] = *(const u32x4*)&sB[((kb*4+n)*64 + l)*4];
}
// repack this wave's single m-tile (with relu) into B-frag LDS layout
__device__ __forceinline__ void repack_one(const f32x4 (&acc)[4], unsigned* sB,
                                           int m, int gq, int cL)
{
    #pragma unroll
    for (int n=0;n<4;n++){
        float v0 = fmaxf(acc[n][0],0.f), v1 = fmaxf(acc[n][1],0.f);
        float v2 = fmaxf(acc[n][2],0.f), v3 = fmaxf(acc[n][3],0.f);
        int gd = 2*(m&1) + (gq>>1);
        int dw = (((m>>1)*4 + n)*64 + 16*gd + cL)*4 + 2*(gq&1);
        sB[dw]   = pk2(v0,v1);
        sB[dw+1] = pk2(v2,v3);
    }
}

// ---------------------------------------------------------------------------
// K0: pack all weights into MFMA A-frags. grid 255 x 64. (unchanged)
// ---------------------------------------------------------------------------
__global__ __launch_bounds__(64)
void k0_pack(const float* __restrict__ ne_W, const float* __restrict__ ee_W,
             const float* __restrict__ ep0_W1, const float* __restrict__ ep0_W2,
             const float* __restrict__ ep1_W1, const float* __restrict__ ep1_W2,
             const float* __restrict__ np_W1, const float* __restrict__ np_W2,
             const float* __restrict__ pred_W1, const float* __restrict__ pred_W2,
             unsigned* __restrict__ pk_e, unsigned* __restrict__ pk_n)
{
    int t = blockIdx.x, l = threadIdx.x;
    int cL = l & 15, gq = l >> 4;
    if (t < 108) {                         // edge-side, hi only
        int mat = t/18, tt = t%18, mt = tt/3, kb = tt%3;
        const float* mats[6] = { ep0_W1 + 2*HH*HH, ep0_W2, ep1_W1 + 2*HH*HH,
                                 ep1_W2, pred_W1, pred_W1 + HH*HH };
        const float* src = mats[mat];
        u32x4 d;
        #pragma unroll
        for (int p=0;p<4;p++){
            int k = 32*kb + 8*gq + 2*p;
            d[p] = pk2(src[k*HH + 16*mt + cL], src[(k+1)*HH + 16*mt + cL]);
        }
        *(u32x4*)&pk_e[mat*4608 + (mt*3+kb)*256 + l*4] = d;
    } else if (t < 111) {                  // pred_W2 zero-padded to 16 cols
        int kb = t - 108;
        u32x4 d;
        #pragma unroll
        for (int p=0;p<4;p++){
            int k = 32*kb + 8*gq + 2*p;
            float lo = (cL < 2) ? pred_W2[k*2 + cL]     : 0.f;
            float hi = (cL < 2) ? pred_W2[(k+1)*2 + cL] : 0.f;
            d[p] = pk2(lo, hi);
        }
        *(u32x4*)&pk_e[PE_P2 + kb*256 + l*4] = d;
    } else {
        int u = t - 111;
        if (u < 18) {                      // K=32 node mats: neW, Wr, Ws (hi+lo)
            int mat = u/6, mt = u%6;
            const float* srcs[3] = { ne_W, ee_W, ee_W + DD*HH };
            const float* src = srcs[mat];
            u32x4 dh, dl;
            #pragma unroll
            for (int p=0;p<4;p++){
                int k = 8*gq + 2*p;
                unsigned th, tl;
                split2(src[k*HH + 16*mt + cL], src[(k+1)*HH + 16*mt + cL], th, tl);
                dh[p] = th; dl[p] = tl;
            }
            int base = mat*3072 + mt*256 + l*4;
            *(u32x4*)&pk_n[base]        = dh;
            *(u32x4*)&pk_n[base + 1536] = dl;
        } else {                           // K=96 node mats (hi+lo)
            int u2 = u-18, mat = u2/18, tt = u2%18, mt = tt/3, kb = tt%3;
            u32x4 dh, dl;
            #pragma unroll
            for (int p=0;p<4;p++){
                int k = 32*kb + 8*gq + 2*p, col = 16*mt + cL;
                float v0, v1;
                if (mat == 2) {            // Wn12 = Wn1 + Wn2
                    v0 = np_W1[k*HH+col]     + np_W1[(HH+k)*HH+col];
                    v1 = np_W1[(k+1)*HH+col] + np_W1[(HH+k+1)*HH+col];
                } else {
                    const float* src = (mat==0) ? ep0_W1
                                     : (mat==1) ? ep0_W1 + HH*HH
                                     : (mat==3) ? np_W1 + 2*HH*HH
                                     : (mat==4) ? np_W2
                                     : (mat==5) ? ep1_W1
                                     :            ep1_W1 + HH*HH;
                    v0 = src[k*HH+col]; v1 = src[(k+1)*HH+col];
                }
                unsigned th, tl;
                split2(v0, v1, th, tl);
                dh[p] = th; dl[p] = tl;
            }
            int base = PN_ER0 + mat*9216 + (mt*3+kb)*256 + l*4;
            *(u32x4*)&pk_n[base]        = dh;
            *(u32x4*)&pk_n[base + 4608] = dl;
        }
    }
}

// ---------------------------------------------------------------------------
// K1: node encode + step-0 projections. grid 128 x 384. (unchanged)
// ---------------------------------------------------------------------------
__global__ __launch_bounds__(384)
void k1_node(const float* __restrict__ node_rep,
             const float* __restrict__ ne_b, const float* __restrict__ ee_b,
             const float* __restrict__ ep0_b1,
             const unsigned* __restrict__ pk_n,
             float* __restrict__ wr_t, float* __restrict__ ws_t,
             float* __restrict__ ner0_t, float* __restrict__ nes0_t,
             float* __restrict__ enc_t)
{
    int blk = blockIdx.x, tid = threadIdx.x;
    int br = blk >> 2, chunk = blk & 3;
    int b = br >> 3, r = br & 7;
    int w = tid >> 6, l = tid & 63;
    int cL = l & 15, gq = l >> 4;
    int col = 16*chunk + cL;
    __shared__ float sN[DD*16];                    // node chunk [32 feats][16 cols]
    __shared__ __align__(16) float sF[HH*LSTR];    // repack buffer [96][17]
    size_t brb = (size_t)br * HH * NN;

    for (int idx = tid; idx < 512; idx += 384){
        int row = idx >> 5, k = idx & 31;
        sN[k*16 + row] = node_rep[((size_t)((b*NN + 16*chunk + row)*RR + r))*DD + k];
    }
    __syncthreads();

    u32x4 nBh, nBl;
    #pragma unroll
    for (int p=0;p<4;p++){
        int k = 8*gq + 2*p;
        unsigned h, lo;
        split2(sN[k*16 + cL], sN[(k+1)*16 + cL], h, lo);
        nBh[p] = h; nBl[p] = lo;
    }

    f32x4 acc;

    cinit1(acc, ne_b, w, gq);
    gemm_1m(acc, pk_n+PN_NEW, pk_n+PN_NEW+1536, w, l, nBh, nBl);
    relu1(acc);
    storeT1(acc, enc_t + brb, w, gq, col);
    toLds1(acc, sF, w, gq, cL);
    __syncthreads();

    cinit1(acc, ep0_b1, w, gq);
    gemm96_1m(acc, pk_n+PN_ER0, pk_n+PN_ER0+4608, w, l, gq, cL, sF);
    storeT1(acc, ner0_t + brb, w, gq, col);

    #pragma unroll
    for (int q=0;q<4;q++) acc[q] = 0.f;
    gemm96_1m(acc, pk_n+PN_ES0, pk_n+PN_ES0+4608, w, l, gq, cL, sF);
    storeT1(acc, nes0_t + brb, w, gq, col);

    cinit1(acc, ee_b, w, gq);
    gemm_1m(acc, pk_n+PN_WR, pk_n+PN_WR+1536, w, l, nBh, nBl);
    storeT1(acc, wr_t + brb, w, gq, col);

    #pragma unroll
    for (int q=0;q<4;q++) acc[q] = 0.f;
    gemm_1m(acc, pk_n+PN_WS, pk_n+PN_WS+1536, w, l, nBh, nBl);
    storeT1(acc, ws_t + brb, w, gq, col);
}

// ---------------------------------------------------------------------------
// K2: edge prop step 0 via MFMA. block = 384 (6 waves, 1 m-tile/wave).
// ---------------------------------------------------------------------------
__global__ __launch_bounds__(384)
void k2_edge0(const float* __restrict__ wr_t, const float* __restrict__ ws_t,
              const float* __restrict__ ner0_t, const float* __restrict__ nes0_t,
              const unsigned* __restrict__ pk_e,
              const float* __restrict__ ep0_b2,
              unsigned* __restrict__ ee0f, float* __restrict__ agg_t)
{
    int g = blockIdx.x, tid = threadIdx.x;
    int w = tid >> 6, l = tid & 63;
    int b = g >> 9, r = g & 7, i = (g >> 3) & 63;
    int cL = l & 15, gq = l >> 4;
    size_t brb = (size_t)(b*RR + r)*HH*NN;
    const float* wrt = wr_t   + brb;
    const float* nrt = ner0_t + brb;
    const float* wst = ws_t   + brb;
    const float* nst = nes0_t + brb;
    __shared__ __align__(16) unsigned sB[3072];

    // C init: ner0' + nes0 (this wave's m-tile)
    f32x4 acc[4];
    #pragma unroll
    for (int q=0;q<4;q++){
        int c = 16*w + 4*gq + q;
        float nr = nrt[c*NN + i];
        #pragma unroll
        for (int n=0;n<4;n++) acc[n][q] = nr + nst[c*NN + 16*n + cL];
    }

    // GEMM1: t0 = Ee0^T @ edge_enc^T
    #pragma unroll
    for (int kb=0;kb<3;kb++){
        u32x4 Bk[4];
        build_ee_kb(Bk, wrt, wst, i, kb, gq, cL);
        egemm1_kb(acc, pk_e + PE_EE0, w, kb, l, Bk);
    }
    repack_one(acc, sB, w, gq, cL);
    __syncthreads();

    // GEMM2: ee0 = W20^T @ t0^T
    einit1(acc, ep0_b2, w, gq);
    #pragma unroll
    for (int kb=0;kb<3;kb++){
        u32x4 Bk[4];
        load_sB_kb(Bk, sB, kb, l);
        egemm1_kb(acc, pk_e + PE_W20, w, kb, l, Bk);
    }
    #pragma unroll
    for (int n=0;n<4;n++)
      #pragma unroll
      for (int q=0;q<4;q++) acc[n][q] = fmaxf(acc[n][q], 0.f);

    // store ee0 frags (B-layout bf16, this wave's m-tile) + agg reduce
    unsigned* eo = ee0f + (size_t)g*3072;
    #pragma unroll
    for (int n=0;n<4;n++){
        int gd = 2*(w&1) + (gq>>1);
        int dw = (((w>>1)*4 + n)*64 + 16*gd + cL)*4 + 2*(gq&1);
        eo[dw]   = pk2(acc[n][0], acc[n][1]);
        eo[dw+1] = pk2(acc[n][2], acc[n][3]);
    }
    #pragma unroll
    for (int q=0;q<4;q++){
        float s = acc[0][q] + acc[1][q] + acc[2][q] + acc[3][q];
        s += __shfl_xor(s, 1);
        s += __shfl_xor(s, 2);
        s += __shfl_xor(s, 4);
        s += __shfl_xor(s, 8);
        if (cL == 0) agg_t[brb + (16*w + 4*gq + q)*NN + i] = s;
    }
}

// ---------------------------------------------------------------------------
// K3: node update + step-1 projections. grid 128 x 384. (unchanged)
// ---------------------------------------------------------------------------
__global__ __launch_bounds__(384)
void k3_node(const float* __restrict__ enc_t_g, const float* __restrict__ agg_t_g,
             const float* __restrict__ np_b1, const float* __restrict__ np_b2,
             const float* __restrict__ ep1_b1,
             const unsigned* __restrict__ pk_n,
             float* __restrict__ ner1_t, float* __restrict__ nes1_t)
{
    int blk = blockIdx.x, tid = threadIdx.x;
    int br = blk >> 2, chunk = blk & 3;
    int w = tid >> 6, l = tid & 63;
    int cL = l & 15, gq = l >> 4;
    int col = 16*chunk + cL;
    __shared__ __align__(16) float sE[HH*LSTR], sA[HH*LSTR], sF[HH*LSTR];
    size_t brb = (size_t)br * HH * NN;
    const float* enc_t = enc_t_g + brb;
    const float* agg_t = agg_t_g + brb;

    for (int idx = tid; idx < HH*16; idx += 384){
        int f = idx >> 4, c = idx & 15;
        sE[f*LSTR + c] = enc_t[f*NN + 16*chunk + c];
        sA[f*LSTR + c] = agg_t[f*NN + 16*chunk + c];
    }
    __syncthreads();

    f32x4 acc;

    cinit1(acc, np_b1, w, gq);
    gemm96_1m(acc, pk_n+PN_WN12, pk_n+PN_WN12+4608, w, l, gq, cL, sE);
    gemm96_1m(acc, pk_n+PN_WN3,  pk_n+PN_WN3+4608,  w, l, gq, cL, sA);
    relu1(acc);
    toLds1(acc, sF, w, gq, cL);
    __syncthreads();

    cinit1(acc, np_b2, w, gq);
    gemm96_1m(acc, pk_n+PN_NPW2, pk_n+PN_NPW2+4608, w, l, gq, cL, sF);
    relu1(acc);
    __syncthreads();
    toLds1(acc, sF, w, gq, cL);
    __syncthreads();

    cinit1(acc, ep1_b1, w, gq);
    gemm96_1m(acc, pk_n+PN_ER1, pk_n+PN_ER1+4608, w, l, gq, cL, sF);
    storeT1(acc, ner1_t + brb, w, gq, col);

    #pragma unroll
    for (int q=0;q<4;q++) acc[q] = 0.f;
    gemm96_1m(acc, pk_n+PN_ES1, pk_n+PN_ES1+4608, w, l, gq, cL, sF);
    storeT1(acc, nes1_t + brb, w, gq, col);
}

// ---------------------------------------------------------------------------
// K4: edge prop step 1 + prediction head. block = 384 (6 waves, 1 m-tile/wave).
// ---------------------------------------------------------------------------
__global__ __launch_bounds__(384)
void k4_edge1(const float* __restrict__ wr_t, const float* __restrict__ ws_t,
              const float* __restrict__ ner1_t, const float* __restrict__ nes1_t,
              const unsigned* __restrict__ pk_e,
              const unsigned* __restrict__ ee0f,
              const float* __restrict__ ep1_b2,
              const float* __restrict__ pred_b1, const float* __restrict__ pred_b2,
              float* __restrict__ out)
{
    int g = blockIdx.x, tid = threadIdx.x;
    int w = tid >> 6, l = tid & 63;
    int b = g >> 9, i = (g >> 3) & 63, r = g & 7;
    int cL = l & 15, gq = l >> 4;
    size_t brb = (size_t)(b*RR + r)*HH*NN;
    const float* wrt = wr_t   + brb;
    const float* wst = ws_t   + brb;
    const float* nrt = ner1_t + brb;
    const float* nst = nes1_t + brb;
    __shared__ __align__(16) unsigned sB[3072];

    const u32x4* e0p = (const u32x4*)ee0f + (size_t)g*768;

    // C init: ner1' + nes1
    f32x4 acc[4];
    #pragma unroll
    for (int q=0;q<4;q++){
        int c = 16*w + 4*gq + q;
        float nr = nrt[c*NN + i];
        #pragma unroll
        for (int n=0;n<4;n++) acc[n][q] = nr + nst[c*NN + 16*n + cL];
    }

    // GEMM1: t1 = Ee1^T @ ee0^T
    #pragma unroll
    for (int kb=0;kb<3;kb++){
        u32x4 Bk[4];
        #pragma unroll
        for (int n=0;n<4;n++) Bk[n] = e0p[(kb*4+n)*64 + l];
        egemm1_kb(acc, pk_e + PE_EE1, w, kb, l, Bk);
    }
    repack_one(acc, sB, w, gq, cL);              // t1 -> sB
    __syncthreads();

    // GEMM2: ee1 = W21^T @ t1^T
    einit1(acc, ep1_b2, w, gq);
    #pragma unroll
    for (int kb=0;kb<3;kb++){
        u32x4 Bk[4];
        load_sB_kb(Bk, sB, kb, l);
        egemm1_kb(acc, pk_e + PE_W21, w, kb, l, Bk);
    }
    __syncthreads();                             // drain t1 reads
    repack_one(acc, sB, w, gq, cL);              // ee1 -> sB
    __syncthreads();

    // GEMM3: tp = pred_b1 + Pe^T @ ee1^T
    einit1(acc, pred_b1, w, gq);
    #pragma unroll
    for (int kb=0;kb<3;kb++){
        u32x4 Bk[4];
        load_sB_kb(Bk, sB, kb, l);
        egemm1_kb(acc, pk_e + PE_PE, w, kb, l, Bk);
    }
    __syncthreads();                             // drain ee1 reads

    // GEMM4: tp += Pc^T @ edge_enc^T
    #pragma unroll
    for (int kb=0;kb<3;kb++){
        u32x4 Bk[4];
        build_ee_kb(Bk, wrt, wst, i, kb, gq, cL);
        egemm1_kb(acc, pk_e + PE_PC, w, kb, l, Bk);
    }
    repack_one(acc, sB, w, gq, cL);              // tp -> sB
    __syncthreads();

    // GEMM5: out = P2^T @ tp^T (rows 0,1 valid); wave w<4 handles n = w
    if (w < 4) {
        f32x4 c5;
        c5[0] = (gq == 0) ? pred_b2[0] : 0.f;
        c5[1] = (gq == 0) ? pred_b2[1] : 0.f;
        c5[2] = 0.f; c5[3] = 0.f;
        #pragma unroll
        for (int kb=0;kb<3;kb++){
            bf16x8 A2 = __builtin_bit_cast(bf16x8, *(const u32x4*)&pk_e[PE_P2 + (kb*64 + l)*4]);
            bf16x8 Bf = __builtin_bit_cast(bf16x8, *(const u32x4*)&sB[((kb*4+w)*64 + l)*4]);
            c5 = MFMA16(A2, Bf, c5);
        }
        if (gq == 0) {
            float2* o2 = (float2*)out;
            size_t j = 16*w + cL;
            o2[(((size_t)(b*NN + i))*NN + j)*RR + r] = make_float2(c5[0], c5[1]);
        }
    }
}

// ---------------------------------------------------------------------------
extern "C" void kernel_launch(void* const* d_in, const int* in_sizes, int n_in,
                              void* d_out, int out_size, void* d_ws, size_t ws_size,
                              hipStream_t stream)
{
    const float* node_rep = (const float*)d_in[0];
    const float* ne_W    = (const float*)d_in[1];
    const float* ne_b    = (const float*)d_in[2];
    const float* ee_W    = (const float*)d_in[3];
    const float* ee_b    = (const float*)d_in[4];
    const float* np_W1   = (const float*)d_in[5];
    const float* np_b1   = (const float*)d_in[6];
    const float* np_W2   = (const float*)d_in[7];
    const float* np_b2   = (const float*)d_in[8];
    const float* ep0_W1  = (const float*)d_in[9];
    const float* ep0_b1  = (const float*)d_in[10];
    const float* ep0_W2  = (const float*)d_in[11];
    const float* ep0_b2  = (const float*)d_in[12];
    const float* ep1_W1  = (const float*)d_in[13];
    const float* ep1_b1  = (const float*)d_in[14];
    const float* ep1_W2  = (const float*)d_in[15];
    const float* ep1_b2  = (const float*)d_in[16];
    const float* pred_W1 = (const float*)d_in[17];
    const float* pred_b1 = (const float*)d_in[18];
    const float* pred_W2 = (const float*)d_in[19];
    const float* pred_b2 = (const float*)d_in[20];
    float* wsf = (float*)d_ws;
    float* out = (float*)d_out;

    float* wr_t   = wsf + OFF_WR_T;
    float* ws_t   = wsf + OFF_WS_T;
    float* ner0_t = wsf + OFF_NER0;
    float* nes0_t = wsf + OFF_NES0;
    float* ner1_t = wsf + OFF_NER1;
    float* nes1_t = wsf + OFF_NES1;
    float* enc_t  = wsf + OFF_ENCT;
    float* agg_t  = wsf + OFF_AGGT;
    unsigned* pk_e = (unsigned*)(wsf + OFF_PKE);
    unsigned* pk_n = (unsigned*)(wsf + OFF_PKN);
    unsigned* ee0f = (unsigned*)(wsf + OFF_EE0F);

    k0_pack<<<255, 64, 0, stream>>>(ne_W, ee_W, ep0_W1, ep0_W2, ep1_W1, ep1_W2,
                                    np_W1, np_W2, pred_W1, pred_W2, pk_e, pk_n);

    k1_node<<<128, 384, 0, stream>>>(node_rep, ne_b, ee_b, ep0_b1, pk_n,
                                     wr_t, ws_t, ner0_t, nes0_t, enc_t);

    k2_edge0<<<NGROUP, 384, 0, stream>>>(wr_t, ws_t, ner0_t, nes0_t, pk_e, ep0_b2,
                                         ee0f, agg_t);

    k3_node<<<128, 384, 0, stream>>>(enc_t, agg_t, np_b1, np_b2, ep1_b1, pk_n,
                                     ner1_t, nes1_t);

    k4_edge1<<<NGROUP, 384, 0, stream>>>(wr_t, ws_t, ner1_t, nes1_t, pk_e, ee0f,
                                         ep1_b2, pred_b1, pred_b2, out);
}

// Round 11
// 67.280 us; speedup vs baseline: 1.2930x; 1.2930x over previous
//
#include <hip/hip_runtime.h>
#include <hip/hip_bf16.h>

#define BB 4
#define NN 64
#define RR 8
#define DD 32
#define HH 96
#define NGROUP (BB*NN*RR)   // 2048
#define LSTR 17             // padded LDS stride (floats) for node repack buffer

// workspace float offsets — all node-side tensors transposed [b*8+r][feat][node]
#define OFF_WR_T  0
#define OFF_WS_T  196608
#define OFF_NER0  393216
#define OFF_NES0  589824
#define OFF_NER1  786432
#define OFF_NES1  983040
#define OFF_ENCT  1179648
#define OFF_AGGT  1376256
#define OFF_PKE   1572864      // edge-side packed weights (hi only), 28416 u32
#define OFF_EE0F  1675008      // ee0 in B-frag bf16 form, 2048*3072 u32

// pk_e u32 offsets (frag = 256 u32; 96x96 mat = 18 frags = 4608)
#define PE_EE0  0
#define PE_W20  4608
#define PE_EE1  9216
#define PE_W21  13824
#define PE_PE   18432
#define PE_PC   23040
#define PE_P2   27648

typedef __attribute__((ext_vector_type(4))) float f32x4;
typedef __attribute__((ext_vector_type(8))) short bf16x8;
typedef __attribute__((ext_vector_type(4))) unsigned int u32x4;

__device__ __forceinline__ unsigned int pk2(float lo, float hi){
    unsigned short a = __builtin_bit_cast(unsigned short, __float2bfloat16(lo));
    unsigned short b = __builtin_bit_cast(unsigned short, __float2bfloat16(hi));
    return (unsigned)a | ((unsigned)b << 16);
}
// split v into bf16 hi + bf16 lo residual (x ~ hi + lo to ~2^-17 rel)
__device__ __forceinline__ void split2(float v0, float v1, unsigned &h, unsigned &lo){
    float h0 = __bfloat162float(__float2bfloat16(v0));
    float h1 = __bfloat162float(__float2bfloat16(v1));
    h  = pk2(v0, v1);
    lo = pk2(v0 - h0, v1 - h1);
}

#define MFMA16(A,B,C) __builtin_amdgcn_mfma_f32_16x16x32_bf16((A),(B),(C),0,0,0)

// ============ node-kernel helpers: on-the-fly A-frags (no pk_n) =============
// Reproduces bit-exactly the old k0 packing for lane l, tile (mt, kb).
__device__ __forceinline__ void buildA(const float* __restrict__ W, int mt, int kb,
                                       int gq, int cL, u32x4 &Ah, u32x4 &Al){
    #pragma unroll
    for (int p=0;p<4;p++){
        int k = 32*kb + 8*gq + 2*p;
        unsigned h, lo;
        split2(W[k*HH + 16*mt + cL], W[(k+1)*HH + 16*mt + cL], h, lo);
        Ah[p] = h; Al[p] = lo;
    }
}
// Wn12 = Wn1 + Wn2 fold (summed before split — identical to old k0)
__device__ __forceinline__ void buildA2(const float* __restrict__ W1,
                                        const float* __restrict__ W2, int mt, int kb,
                                        int gq, int cL, u32x4 &Ah, u32x4 &Al){
    #pragma unroll
    for (int p=0;p<4;p++){
        int k = 32*kb + 8*gq + 2*p;
        unsigned h, lo;
        split2(W1[k*HH+16*mt+cL] + W2[k*HH+16*mt+cL],
               W1[(k+1)*HH+16*mt+cL] + W2[(k+1)*HH+16*mt+cL], h, lo);
        Ah[p] = h; Al[p] = lo;
    }
}
__device__ __forceinline__ void gemm_fly(f32x4 &acc, const u32x4 &Ah, const u32x4 &Al,
                                         const u32x4 &Bh, const u32x4 &Bl){
    bf16x8 ah = __builtin_bit_cast(bf16x8, Ah);
    bf16x8 al = __builtin_bit_cast(bf16x8, Al);
    bf16x8 bh = __builtin_bit_cast(bf16x8, Bh);
    bf16x8 bl = __builtin_bit_cast(bf16x8, Bl);
    acc = MFMA16(ah, bh, acc);
    acc = MFMA16(ah, bl, acc);
    acc = MFMA16(al, bh, acc);
}
__device__ __forceinline__ void buildB_lds(const float* sF, int kb, int gq, int cL,
                                           u32x4 &Bh, u32x4 &Bl){
    #pragma unroll
    for (int p=0;p<4;p++){
        int f = 32*kb + 8*gq + 2*p;
        unsigned h, lo;
        split2(sF[f*LSTR + cL], sF[(f+1)*LSTR + cL], h, lo);
        Bh[p] = h; Bl[p] = lo;
    }
}
// K=96 split GEMM (one m-tile), B from LDS buffer, A on the fly
__device__ __forceinline__ void gemm96_fly(f32x4 &acc, const float* __restrict__ W,
    int w, int gq, int cL, const float* sF)
{
    #pragma unroll
    for (int kb=0;kb<3;kb++){
        u32x4 Bh, Bl, Ah, Al;
        buildB_lds(sF, kb, gq, cL, Bh, Bl);
        buildA(W, w, kb, gq, cL, Ah, Al);
        gemm_fly(acc, Ah, Al, Bh, Bl);
    }
}
__device__ __forceinline__ void gemm96_fly2(f32x4 &acc, const float* __restrict__ W1,
    const float* __restrict__ W2, int w, int gq, int cL, const float* sF)
{
    #pragma unroll
    for (int kb=0;kb<3;kb++){
        u32x4 Bh, Bl, Ah, Al;
        buildB_lds(sF, kb, gq, cL, Bh, Bl);
        buildA2(W1, W2, w, kb, gq, cL, Ah, Al);
        gemm_fly(acc, Ah, Al, Bh, Bl);
    }
}
__device__ __forceinline__ void relu1(f32x4 &acc){
    #pragma unroll
    for (int q=0;q<4;q++) acc[q] = fmaxf(acc[q], 0.f);
}
__device__ __forceinline__ void cinit1(f32x4 &acc, const float* __restrict__ bv, int w, int gq){
    #pragma unroll
    for (int q=0;q<4;q++) acc[q] = bv[16*w+4*gq+q];
}
__device__ __forceinline__ void storeT1(const f32x4 &acc, float* __restrict__ dst,
                                        int w, int gq, int col){
    #pragma unroll
    for (int q=0;q<4;q++) dst[(16*w+4*gq+q)*NN + col] = acc[q];
}
__device__ __forceinline__ void toLds1(const f32x4 &acc, float* sF, int w, int gq, int cL){
    #pragma unroll
    for (int q=0;q<4;q++) sF[(16*w+4*gq+q)*LSTR + cL] = acc[q];
}

// ================= edge-kernel helpers (2 waves/block, 3 m-tiles/wave) ======
__device__ __forceinline__ void einit_b(f32x4 (&acc)[3][4], const float* __restrict__ bv,
                                        int mBase, int gq){
    #pragma unroll
    for (int mi=0;mi<3;mi++)
      #pragma unroll
      for (int q=0;q<4;q++){
        float x = bv[16*(mBase+mi)+4*gq+q];
        #pragma unroll
        for (int n=0;n<4;n++) acc[mi][n][q] = x;
      }
}
__device__ __forceinline__ void egemm_kb(f32x4 (&acc)[3][4],
    const unsigned* __restrict__ Apk, int mBase, int kb, int l, const u32x4 (&Bk)[4])
{
    #pragma unroll
    for (int mi=0;mi<3;mi++){
        bf16x8 a = __builtin_bit_cast(bf16x8, *(const u32x4*)&Apk[(((mBase+mi)*3+kb)*64 + l)*4]);
        #pragma unroll
        for (int n=0;n<4;n++){
            bf16x8 bf = __builtin_bit_cast(bf16x8, Bk[n]);
            acc[mi][n] = MFMA16(a, bf, acc[mi][n]);
        }
    }
}
__device__ __forceinline__ void build_ee_kb(u32x4 (&Bk)[4],
    const float* __restrict__ wrt, const float* __restrict__ wst,
    int i, int kb, int gq, int cL)
{
    #pragma unroll
    for (int n=0;n<4;n++)
      #pragma unroll
      for (int p=0;p<4;p++){
        int h = 32*kb + 8*gq + 2*p;
        int j = 16*n + cL;
        float a0 = fmaxf(wrt[h*NN + i]     + wst[h*NN + j],     0.f);
        float a1 = fmaxf(wrt[(h+1)*NN + i] + wst[(h+1)*NN + j], 0.f);
        Bk[n][p] = pk2(a0, a1);
      }
}
__device__ __forceinline__ void load_sB_kb(u32x4 (&Bk)[4], const unsigned* sB, int kb, int l){
    #pragma unroll
    for (int n=0;n<4;n++) Bk[n] = *(const u32x4*)&sB[((kb*4+n)*64 + l)*4];
}
__device__ __forceinline__ void repack_half(const f32x4 (&acc)[3][4], unsigned* sB,
                                            int mBase, int gq, int cL)
{
    #pragma unroll
    for (int mi=0;mi<3;mi++){
      int m = mBase+mi;
      #pragma unroll
      for (int n=0;n<4;n++){
        float v0 = fmaxf(acc[mi][n][0],0.f), v1 = fmaxf(acc[mi][n][1],0.f);
        float v2 = fmaxf(acc[mi][n][2],0.f), v3 = fmaxf(acc[mi][n][3],0.f);
        int gd = 2*(m&1) + (gq>>1);
        int dw = (((m>>1)*4 + n)*64 + 16*gd + cL)*4 + 2*(gq&1);
        sB[dw]   = pk2(v0,v1);
        sB[dw+1] = pk2(v2,v3);
      }
    }
}

// ---------------------------------------------------------------------------
// K1: node encode + step-0 projections (A-frags on the fly), grid 239 x 384.
// Blocks 0..127: node work. Blocks 128..238: pk_e edge-weight packing riders.
// ---------------------------------------------------------------------------
__global__ __launch_bounds__(384)
void k1_node(const float* __restrict__ node_rep,
             const float* __restrict__ ne_W, const float* __restrict__ ne_b,
             const float* __restrict__ ee_W, const float* __restrict__ ee_b,
             const float* __restrict__ ep0_W1, const float* __restrict__ ep0_b1,
             const float* __restrict__ ep0_W2, const float* __restrict__ ep1_W1,
             const float* __restrict__ ep1_W2, const float* __restrict__ pred_W1,
             const float* __restrict__ pred_W2,
             unsigned* __restrict__ pk_e,
             float* __restrict__ wr_t, float* __restrict__ ws_t,
             float* __restrict__ ner0_t, float* __restrict__ nes0_t,
             float* __restrict__ enc_t)
{
    int blk = blockIdx.x, tid = threadIdx.x;
    if (blk >= 128) {                    // pk_e packing riders (64 threads used)
        if (tid < 64) {
            int t = blk - 128, l = tid;
            int cL = l & 15, gq = l >> 4;
            if (t < 108) {
                int mat = t/18, tt = t%18, mt = tt/3, kb = tt%3;
                const float* mats[6] = { ep0_W1 + 2*HH*HH, ep0_W2, ep1_W1 + 2*HH*HH,
                                         ep1_W2, pred_W1, pred_W1 + HH*HH };
                const float* src = mats[mat];
                u32x4 d;
                #pragma unroll
                for (int p=0;p<4;p++){
                    int k = 32*kb + 8*gq + 2*p;
                    d[p] = pk2(src[k*HH + 16*mt + cL], src[(k+1)*HH + 16*mt + cL]);
                }
                *(u32x4*)&pk_e[mat*4608 + (mt*3+kb)*256 + l*4] = d;
            } else {                     // pred_W2 zero-padded to 16 cols
                int kb = t - 108;
                u32x4 d;
                #pragma unroll
                for (int p=0;p<4;p++){
                    int k = 32*kb + 8*gq + 2*p;
                    float lo = (cL < 2) ? pred_W2[k*2 + cL]     : 0.f;
                    float hi = (cL < 2) ? pred_W2[(k+1)*2 + cL] : 0.f;
                    d[p] = pk2(lo, hi);
                }
                *(u32x4*)&pk_e[PE_P2 + kb*256 + l*4] = d;
            }
        }
        return;
    }

    int br = blk >> 2, chunk = blk & 3;
    int b = br >> 3, r = br & 7;
    int w = tid >> 6, l = tid & 63;
    int cL = l & 15, gq = l >> 4;
    int col = 16*chunk + cL;
    __shared__ float sN[DD*16];                    // node chunk [32 feats][16 cols]
    __shared__ __align__(16) float sF[HH*LSTR];    // repack buffer [96][17]
    size_t brb = (size_t)br * HH * NN;

    for (int idx = tid; idx < 512; idx += 384){
        int row = idx >> 5, k = idx & 31;
        sN[k*16 + row] = node_rep[((size_t)((b*NN + 16*chunk + row)*RR + r))*DD + k];
    }
    __syncthreads();

    u32x4 nBh, nBl;
    #pragma unroll
    for (int p=0;p<4;p++){
        int k = 8*gq + 2*p;
        unsigned h, lo;
        split2(sN[k*16 + cL], sN[(k+1)*16 + cL], h, lo);
        nBh[p] = h; nBl[p] = lo;
    }

    f32x4 acc;
    u32x4 Ah, Al;

    // enc = relu(node @ neW + ne_b)   (wave w -> m-tile w)
    cinit1(acc, ne_b, w, gq);
    buildA(ne_W, w, 0, gq, cL, Ah, Al);
    gemm_fly(acc, Ah, Al, nBh, nBl);
    relu1(acc);
    storeT1(acc, enc_t + brb, w, gq, col);
    toLds1(acc, sF, w, gq, cL);
    __syncthreads();

    // ner0 = enc @ Er0 + ep0_b1
    cinit1(acc, ep0_b1, w, gq);
    gemm96_fly(acc, ep0_W1, w, gq, cL, sF);
    storeT1(acc, ner0_t + brb, w, gq, col);

    // nes0 = enc @ Es0
    #pragma unroll
    for (int q=0;q<4;q++) acc[q] = 0.f;
    gemm96_fly(acc, ep0_W1 + HH*HH, w, gq, cL, sF);
    storeT1(acc, nes0_t + brb, w, gq, col);

    // wr' = node @ Wr + ee_b
    cinit1(acc, ee_b, w, gq);
    buildA(ee_W, w, 0, gq, cL, Ah, Al);
    gemm_fly(acc, Ah, Al, nBh, nBl);
    storeT1(acc, wr_t + brb, w, gq, col);

    // ws = node @ Ws
    #pragma unroll
    for (int q=0;q<4;q++) acc[q] = 0.f;
    buildA(ee_W + DD*HH, w, 0, gq, cL, Ah, Al);
    gemm_fly(acc, Ah, Al, nBh, nBl);
    storeT1(acc, ws_t + brb, w, gq, col);
}

// ---------------------------------------------------------------------------
// K2: edge prop step 0 via MFMA. block = 128 (2 waves, 3 m-tiles/wave) — the
// measured sweet spot (R8): more waves duplicate B-build/C-init overhead.
// ---------------------------------------------------------------------------
__global__ __launch_bounds__(128)
void k2_edge0(const float* __restrict__ wr_t, const float* __restrict__ ws_t,
              const float* __restrict__ ner0_t, const float* __restrict__ nes0_t,
              const unsigned* __restrict__ pk_e,
              const float* __restrict__ ep0_b2,
              unsigned* __restrict__ ee0f, float* __restrict__ agg_t)
{
    int g = blockIdx.x, tid = threadIdx.x;
    int w = tid >> 6, l = tid & 63;
    int b = g >> 9, r = g & 7, i = (g >> 3) & 63;
    int cL = l & 15, gq = l >> 4;
    int mBase = 3*w;
    size_t brb = (size_t)(b*RR + r)*HH*NN;
    const float* wrt = wr_t   + brb;
    const float* nrt = ner0_t + brb;
    const float* wst = ws_t   + brb;
    const float* nst = nes0_t + brb;
    __shared__ __align__(16) unsigned sB[3072];

    f32x4 acc[3][4];
    #pragma unroll
    for (int mi=0;mi<3;mi++)
      #pragma unroll
      for (int q=0;q<4;q++){
        int c = 16*(mBase+mi) + 4*gq + q;
        float nr = nrt[c*NN + i];
        #pragma unroll
        for (int n=0;n<4;n++) acc[mi][n][q] = nr + nst[c*NN + 16*n + cL];
      }

    // GEMM1: t0 = Ee0^T @ edge_enc^T
    #pragma unroll
    for (int kb=0;kb<3;kb++){
        u32x4 Bk[4];
        build_ee_kb(Bk, wrt, wst, i, kb, gq, cL);
        egemm_kb(acc, pk_e + PE_EE0, mBase, kb, l, Bk);
    }
    repack_half(acc, sB, mBase, gq, cL);
    __syncthreads();

    // GEMM2: ee0 = W20^T @ t0^T
    einit_b(acc, ep0_b2, mBase, gq);
    #pragma unroll
    for (int kb=0;kb<3;kb++){
        u32x4 Bk[4];
        load_sB_kb(Bk, sB, kb, l);
        egemm_kb(acc, pk_e + PE_W20, mBase, kb, l, Bk);
    }
    #pragma unroll
    for (int mi=0;mi<3;mi++)
      #pragma unroll
      for (int n=0;n<4;n++)
        #pragma unroll
        for (int q=0;q<4;q++) acc[mi][n][q] = fmaxf(acc[mi][n][q], 0.f);

    unsigned* eo = ee0f + (size_t)g*3072;
    #pragma unroll
    for (int mi=0;mi<3;mi++){
      int m = mBase+mi;
      #pragma unroll
      for (int n=0;n<4;n++){
        int gd = 2*(m&1) + (gq>>1);
        int dw = (((m>>1)*4 + n)*64 + 16*gd + cL)*4 + 2*(gq&1);
        eo[dw]   = pk2(acc[mi][n][0], acc[mi][n][1]);
        eo[dw+1] = pk2(acc[mi][n][2], acc[mi][n][3]);
      }
    }
    #pragma unroll
    for (int mi=0;mi<3;mi++)
      #pragma unroll
      for (int q=0;q<4;q++){
        float s = acc[mi][0][q] + acc[mi][1][q] + acc[mi][2][q] + acc[mi][3][q];
        s += __shfl_xor(s, 1);
        s += __shfl_xor(s, 2);
        s += __shfl_xor(s, 4);
        s += __shfl_xor(s, 8);
        if (cL == 0) agg_t[brb + (16*(mBase+mi) + 4*gq + q)*NN + i] = s;
      }
}

// ---------------------------------------------------------------------------
// K3: node update + step-1 projections (A-frags on the fly). grid 128 x 384.
// ---------------------------------------------------------------------------
__global__ __launch_bounds__(384)
void k3_node(const float* __restrict__ enc_t_g, const float* __restrict__ agg_t_g,
             const float* __restrict__ np_W1, const float* __restrict__ np_b1,
             const float* __restrict__ np_W2, const float* __restrict__ np_b2,
             const float* __restrict__ ep1_W1, const float* __restrict__ ep1_b1,
             float* __restrict__ ner1_t, float* __restrict__ nes1_t)
{
    int blk = blockIdx.x, tid = threadIdx.x;
    int br = blk >> 2, chunk = blk & 3;
    int w = tid >> 6, l = tid & 63;
    int cL = l & 15, gq = l >> 4;
    int col = 16*chunk + cL;
    __shared__ __align__(16) float sE[HH*LSTR], sA[HH*LSTR], sF[HH*LSTR];
    size_t brb = (size_t)br * HH * NN;
    const float* enc_t = enc_t_g + brb;
    const float* agg_t = agg_t_g + brb;

    for (int idx = tid; idx < HH*16; idx += 384){
        int f = idx >> 4, c = idx & 15;
        sE[f*LSTR + c] = enc_t[f*NN + 16*chunk + c];
        sA[f*LSTR + c] = agg_t[f*NN + 16*chunk + c];
    }
    __syncthreads();

    f32x4 acc;

    // t = relu(enc @ Wn12 + agg @ Wn3 + np_b1)
    cinit1(acc, np_b1, w, gq);
    gemm96_fly2(acc, np_W1, np_W1 + HH*HH, w, gq, cL, sE);   // Wn12 fold
    gemm96_fly(acc, np_W1 + 2*HH*HH, w, gq, cL, sA);         // Wn3
    relu1(acc);
    toLds1(acc, sF, w, gq, cL);
    __syncthreads();

    // ne1 = relu(t @ npW2 + np_b2)
    cinit1(acc, np_b2, w, gq);
    gemm96_fly(acc, np_W2, w, gq, cL, sF);
    relu1(acc);
    __syncthreads();                 // drain reads of t before overwrite
    toLds1(acc, sF, w, gq, cL);
    __syncthreads();

    // ner1 = ne1 @ Er1 + ep1_b1
    cinit1(acc, ep1_b1, w, gq);
    gemm96_fly(acc, ep1_W1, w, gq, cL, sF);
    storeT1(acc, ner1_t + brb, w, gq, col);

    // nes1 = ne1 @ Es1
    #pragma unroll
    for (int q=0;q<4;q++) acc[q] = 0.f;
    gemm96_fly(acc, ep1_W1 + HH*HH, w, gq, cL, sF);
    storeT1(acc, nes1_t + brb, w, gq, col);
}

// ---------------------------------------------------------------------------
// K4: edge prop step 1 + prediction head. block = 128 (2 waves, 3 m-tiles/wave).
// ---------------------------------------------------------------------------
__global__ __launch_bounds__(128)
void k4_edge1(const float* __restrict__ wr_t, const float* __restrict__ ws_t,
              const float* __restrict__ ner1_t, const float* __restrict__ nes1_t,
              const unsigned* __restrict__ pk_e,
              const unsigned* __restrict__ ee0f,
              const float* __restrict__ ep1_b2,
              const float* __restrict__ pred_b1, const float* __restrict__ pred_b2,
              float* __restrict__ out)
{
    int g = blockIdx.x, tid = threadIdx.x;
    int w = tid >> 6, l = tid & 63;
    int b = g >> 9, i = (g >> 3) & 63, r = g & 7;
    int cL = l & 15, gq = l >> 4;
    int mBase = 3*w;
    size_t brb = (size_t)(b*RR + r)*HH*NN;
    const float* wrt = wr_t   + brb;
    const float* wst = ws_t   + brb;
    const float* nrt = ner1_t + brb;
    const float* nst = nes1_t + brb;
    __shared__ __align__(16) unsigned sB[3072];

    const u32x4* e0p = (const u32x4*)ee0f + (size_t)g*768;

    f32x4 acc[3][4];
    #pragma unroll
    for (int mi=0;mi<3;mi++)
      #pragma unroll
      for (int q=0;q<4;q++){
        int c = 16*(mBase+mi) + 4*gq + q;
        float nr = nrt[c*NN + i];
        #pragma unroll
        for (int n=0;n<4;n++) acc[mi][n][q] = nr + nst[c*NN + 16*n + cL];
      }

    // GEMM1: t1 = Ee1^T @ ee0^T
    #pragma unroll
    for (int kb=0;kb<3;kb++){
        u32x4 Bk[4];
        #pragma unroll
        for (int n=0;n<4;n++) Bk[n] = e0p[(kb*4+n)*64 + l];
        egemm_kb(acc, pk_e + PE_EE1, mBase, kb, l, Bk);
    }
    repack_half(acc, sB, mBase, gq, cL);         // t1 -> sB
    __syncthreads();

    // GEMM2: ee1 = W21^T @ t1^T
    einit_b(acc, ep1_b2, mBase, gq);
    #pragma unroll
    for (int kb=0;kb<3;kb++){
        u32x4 Bk[4];
        load_sB_kb(Bk, sB, kb, l);
        egemm_kb(acc, pk_e + PE_W21, mBase, kb, l, Bk);
    }
    __syncthreads();                             // drain t1 reads
    repack_half(acc, sB, mBase, gq, cL);         // ee1 -> sB
    __syncthreads();

    // GEMM3: tp = pred_b1 + Pe^T @ ee1^T
    einit_b(acc, pred_b1, mBase, gq);
    #pragma unroll
    for (int kb=0;kb<3;kb++){
        u32x4 Bk[4];
        load_sB_kb(Bk, sB, kb, l);
        egemm_kb(acc, pk_e + PE_PE, mBase, kb, l, Bk);
    }
    __syncthreads();                             // drain ee1 reads

    // GEMM4: tp += Pc^T @ edge_enc^T
    #pragma unroll
    for (int kb=0;kb<3;kb++){
        u32x4 Bk[4];
        build_ee_kb(Bk, wrt, wst, i, kb, gq, cL);
        egemm_kb(acc, pk_e + PE_PC, mBase, kb, l, Bk);
    }
    repack_half(acc, sB, mBase, gq, cL);         // tp -> sB
    __syncthreads();

    // GEMM5: out = P2^T @ tp^T (rows 0,1 valid); wave w handles n = 2w, 2w+1
    f32x4 c5[2];
    #pragma unroll
    for (int nn=0;nn<2;nn++){
        c5[nn][0] = (gq == 0) ? pred_b2[0] : 0.f;
        c5[nn][1] = (gq == 0) ? pred_b2[1] : 0.f;
        c5[nn][2] = 0.f; c5[nn][3] = 0.f;
    }
    #pragma unroll
    for (int kb=0;kb<3;kb++){
        bf16x8 A2 = __builtin_bit_cast(bf16x8, *(const u32x4*)&pk_e[PE_P2 + (kb*64 + l)*4]);
        #pragma unroll
        for (int nn=0;nn<2;nn++){
            int n = 2*w + nn;
            bf16x8 Bf = __builtin_bit_cast(bf16x8, *(const u32x4*)&sB[((kb*4+n)*64 + l)*4]);
            c5[nn] = MFMA16(A2, Bf, c5[nn]);
        }
    }
    if (gq == 0) {
        float2* o2 = (float2*)out;
        #pragma unroll
        for (int nn=0;nn<2;nn++){
            size_t j = 16*(2*w+nn) + cL;
            o2[(((size_t)(b*NN + i))*NN + j)*RR + r] = make_float2(c5[nn][0], c5[nn][1]);
        }
    }
}

// ---------------------------------------------------------------------------
extern "C" void kernel_launch(void* const* d_in, const int* in_sizes, int n_in,
                              void* d_out, int out_size, void* d_ws, size_t ws_size,
                              hipStream_t stream)
{
    const float* node_rep = (const float*)d_in[0];
    const float* ne_W    = (const float*)d_in[1];
    const float* ne_b    = (const float*)d_in[2];
    const float* ee_W    = (const float*)d_in[3];
    const float* ee_b    = (const float*)d_in[4];
    const float* np_W1   = (const float*)d_in[5];
    const float* np_b1   = (const float*)d_in[6];
    const float* np_W2   = (const float*)d_in[7];
    const float* np_b2   = (const float*)d_in[8];
    const float* ep0_W1  = (const float*)d_in[9];
    const float* ep0_b1  = (const float*)d_in[10];
    const float* ep0_W2  = (const float*)d_in[11];
    const float* ep0_b2  = (const float*)d_in[12];
    const float* ep1_W1  = (const float*)d_in[13];
    const float* ep1_b1  = (const float*)d_in[14];
    const float* ep1_W2  = (const float*)d_in[15];
    const float* ep1_b2  = (const float*)d_in[16];
    const float* pred_W1 = (const float*)d_in[17];
    const float* pred_b1 = (const float*)d_in[18];
    const float* pred_W2 = (const float*)d_in[19];
    const float* pred_b2 = (const float*)d_in[20];
    float* wsf = (float*)d_ws;
    float* out = (float*)d_out;

    float* wr_t   = wsf + OFF_WR_T;
    float* ws_t   = wsf + OFF_WS_T;
    float* ner0_t = wsf + OFF_NER0;
    float* nes0_t = wsf + OFF_NES0;
    float* ner1_t = wsf + OFF_NER1;
    float* nes1_t = wsf + OFF_NES1;
    float* enc_t  = wsf + OFF_ENCT;
    float* agg_t  = wsf + OFF_AGGT;
    unsigned* pk_e = (unsigned*)(wsf + OFF_PKE);
    unsigned* ee0f = (unsigned*)(wsf + OFF_EE0F);

    // K1 carries the pk_e packing as rider blocks (blocks 128..238) — k2 is
    // stream-ordered after k1, so pk_e is ready when k2 starts. 4 dispatches.
    k1_node<<<239, 384, 0, stream>>>(node_rep, ne_W, ne_b, ee_W, ee_b,
                                     ep0_W1, ep0_b1,
                                     ep0_W2, ep1_W1, ep1_W2, pred_W1, pred_W2,
                                     pk_e,
                                     wr_t, ws_t, ner0_t, nes0_t, enc_t);

    k2_edge0<<<NGROUP, 128, 0, stream>>>(wr_t, ws_t, ner0_t, nes0_t, pk_e, ep0_b2,
                                         ee0f, agg_t);

    k3_node<<<128, 384, 0, stream>>>(enc_t, agg_t, np_W1, np_b1, np_W2, np_b2,
                                     ep1_W1, ep1_b1, ner1_t, nes1_t);

    k4_edge1<<<NGROUP, 128, 0, stream>>>(wr_t, ws_t, ner1_t, nes1_t, pk_e, ee0f,
                                         ep1_b2, pred_b1, pred_b2, out);
}

// Round 12
// 65.264 us; speedup vs baseline: 1.3330x; 1.0309x over previous
//
#include <hip/hip_runtime.h>
#include <hip/hip_bf16.h>

#define BB 4
#define NN 64
#define RR 8
#define DD 32
#define HH 96
#define NGROUP (BB*NN*RR)   // 2048
#define LSTR 17             // padded LDS stride (floats) for node repack buffer

// workspace float offsets — all node-side tensors transposed [b*8+r][feat][node]
#define OFF_WR_T  0
#define OFF_WS_T  196608
#define OFF_NER0  393216
#define OFF_NES0  589824
#define OFF_NER1  786432
#define OFF_NES1  983040
#define OFF_ENCT  1179648
#define OFF_AGGT  1376256
#define OFF_PKE   1572864      // edge-side packed weights (hi only), 28416 u32
#define OFF_EE0F  1675008      // ee0 in B-frag bf16 form, 2048*3072 u32

// pk_e u32 offsets (frag = 256 u32; 96x96 mat = 18 frags = 4608)
#define PE_EE0  0
#define PE_W20  4608
#define PE_EE1  9216
#define PE_W21  13824
#define PE_PE   18432
#define PE_PC   23040
#define PE_P2   27648

typedef __attribute__((ext_vector_type(4))) float f32x4;
typedef __attribute__((ext_vector_type(8))) short bf16x8;
typedef __attribute__((ext_vector_type(4))) unsigned int u32x4;

__device__ __forceinline__ unsigned int pk2(float lo, float hi){
    unsigned short a = __builtin_bit_cast(unsigned short, __float2bfloat16(lo));
    unsigned short b = __builtin_bit_cast(unsigned short, __float2bfloat16(hi));
    return (unsigned)a | ((unsigned)b << 16);
}
// split v into bf16 hi + bf16 lo residual (x ~ hi + lo to ~2^-17 rel)
__device__ __forceinline__ void split2(float v0, float v1, unsigned &h, unsigned &lo){
    float h0 = __bfloat162float(__float2bfloat16(v0));
    float h1 = __bfloat162float(__float2bfloat16(v1));
    h  = pk2(v0, v1);
    lo = pk2(v0 - h0, v1 - h1);
}

#define MFMA16(A,B,C) __builtin_amdgcn_mfma_f32_16x16x32_bf16((A),(B),(C),0,0,0)

// ============ node-kernel helpers: on-the-fly A-frags (no pk_n) =============
__device__ __forceinline__ void buildA(const float* __restrict__ W, int mt, int kb,
                                       int gq, int cL, u32x4 &Ah, u32x4 &Al){
    #pragma unroll
    for (int p=0;p<4;p++){
        int k = 32*kb + 8*gq + 2*p;
        unsigned h, lo;
        split2(W[k*HH + 16*mt + cL], W[(k+1)*HH + 16*mt + cL], h, lo);
        Ah[p] = h; Al[p] = lo;
    }
}
__device__ __forceinline__ void buildA2(const float* __restrict__ W1,
                                        const float* __restrict__ W2, int mt, int kb,
                                        int gq, int cL, u32x4 &Ah, u32x4 &Al){
    #pragma unroll
    for (int p=0;p<4;p++){
        int k = 32*kb + 8*gq + 2*p;
        unsigned h, lo;
        split2(W1[k*HH+16*mt+cL] + W2[k*HH+16*mt+cL],
               W1[(k+1)*HH+16*mt+cL] + W2[(k+1)*HH+16*mt+cL], h, lo);
        Ah[p] = h; Al[p] = lo;
    }
}
__device__ __forceinline__ void gemm_fly(f32x4 &acc, const u32x4 &Ah, const u32x4 &Al,
                                         const u32x4 &Bh, const u32x4 &Bl){
    bf16x8 ah = __builtin_bit_cast(bf16x8, Ah);
    bf16x8 al = __builtin_bit_cast(bf16x8, Al);
    bf16x8 bh = __builtin_bit_cast(bf16x8, Bh);
    bf16x8 bl = __builtin_bit_cast(bf16x8, Bl);
    acc = MFMA16(ah, bh, acc);
    acc = MFMA16(ah, bl, acc);
    acc = MFMA16(al, bh, acc);
}
__device__ __forceinline__ void buildB_lds(const float* sF, int kb, int gq, int cL,
                                           u32x4 &Bh, u32x4 &Bl){
    #pragma unroll
    for (int p=0;p<4;p++){
        int f = 32*kb + 8*gq + 2*p;
        unsigned h, lo;
        split2(sF[f*LSTR + cL], sF[(f+1)*LSTR + cL], h, lo);
        Bh[p] = h; Bl[p] = lo;
    }
}
__device__ __forceinline__ void gemm96_fly(f32x4 &acc, const float* __restrict__ W,
    int w, int gq, int cL, const float* sF)
{
    #pragma unroll
    for (int kb=0;kb<3;kb++){
        u32x4 Bh, Bl, Ah, Al;
        buildB_lds(sF, kb, gq, cL, Bh, Bl);
        buildA(W, w, kb, gq, cL, Ah, Al);
        gemm_fly(acc, Ah, Al, Bh, Bl);
    }
}
__device__ __forceinline__ void gemm96_fly2(f32x4 &acc, const float* __restrict__ W1,
    const float* __restrict__ W2, int w, int gq, int cL, const float* sF)
{
    #pragma unroll
    for (int kb=0;kb<3;kb++){
        u32x4 Bh, Bl, Ah, Al;
        buildB_lds(sF, kb, gq, cL, Bh, Bl);
        buildA2(W1, W2, w, kb, gq, cL, Ah, Al);
        gemm_fly(acc, Ah, Al, Bh, Bl);
    }
}
__device__ __forceinline__ void relu1(f32x4 &acc){
    #pragma unroll
    for (int q=0;q<4;q++) acc[q] = fmaxf(acc[q], 0.f);
}
__device__ __forceinline__ void cinit1(f32x4 &acc, const float* __restrict__ bv, int w, int gq){
    #pragma unroll
    for (int q=0;q<4;q++) acc[q] = bv[16*w+4*gq+q];
}
__device__ __forceinline__ void storeT1(const f32x4 &acc, float* __restrict__ dst,
                                        int w, int gq, int col){
    #pragma unroll
    for (int q=0;q<4;q++) dst[(16*w+4*gq+q)*NN + col] = acc[q];
}
__device__ __forceinline__ void toLds1(const f32x4 &acc, float* sF, int w, int gq, int cL){
    #pragma unroll
    for (int q=0;q<4;q++) sF[(16*w+4*gq+q)*LSTR + cL] = acc[q];
}

// ================= edge-kernel helpers (2 waves/block, 3 m-tiles/wave) ======
__device__ __forceinline__ void einit_b(f32x4 (&acc)[3][4], const float* __restrict__ bv,
                                        int mBase, int gq){
    #pragma unroll
    for (int mi=0;mi<3;mi++)
      #pragma unroll
      for (int q=0;q<4;q++){
        float x = bv[16*(mBase+mi)+4*gq+q];
        #pragma unroll
        for (int n=0;n<4;n++) acc[mi][n][q] = x;
      }
}
__device__ __forceinline__ void egemm_kb(f32x4 (&acc)[3][4],
    const unsigned* __restrict__ Apk, int mBase, int kb, int l, const u32x4 (&Bk)[4])
{
    #pragma unroll
    for (int mi=0;mi<3;mi++){
        bf16x8 a = __builtin_bit_cast(bf16x8, *(const u32x4*)&Apk[(((mBase+mi)*3+kb)*64 + l)*4]);
        #pragma unroll
        for (int n=0;n<4;n++){
            bf16x8 bf = __builtin_bit_cast(bf16x8, Bk[n]);
            acc[mi][n] = MFMA16(a, bf, acc[mi][n]);
        }
    }
}
__device__ __forceinline__ void build_ee_kb(u32x4 (&Bk)[4],
    const float* __restrict__ wrt, const float* __restrict__ wst,
    int i, int kb, int gq, int cL)
{
    #pragma unroll
    for (int n=0;n<4;n++)
      #pragma unroll
      for (int p=0;p<4;p++){
        int h = 32*kb + 8*gq + 2*p;
        int j = 16*n + cL;
        float a0 = fmaxf(wrt[h*NN + i]     + wst[h*NN + j],     0.f);
        float a1 = fmaxf(wrt[(h+1)*NN + i] + wst[(h+1)*NN + j], 0.f);
        Bk[n][p] = pk2(a0, a1);
      }
}
__device__ __forceinline__ void load_sB_kb(u32x4 (&Bk)[4], const unsigned* sB, int kb, int l){
    #pragma unroll
    for (int n=0;n<4;n++) Bk[n] = *(const u32x4*)&sB[((kb*4+n)*64 + l)*4];
}
__device__ __forceinline__ void repack_half(const f32x4 (&acc)[3][4], unsigned* sB,
                                            int mBase, int gq, int cL)
{
    #pragma unroll
    for (int mi=0;mi<3;mi++){
      int m = mBase+mi;
      #pragma unroll
      for (int n=0;n<4;n++){
        float v0 = fmaxf(acc[mi][n][0],0.f), v1 = fmaxf(acc[mi][n][1],0.f);
        float v2 = fmaxf(acc[mi][n][2],0.f), v3 = fmaxf(acc[mi][n][3],0.f);
        int gd = 2*(m&1) + (gq>>1);
        int dw = (((m>>1)*4 + n)*64 + 16*gd + cL)*4 + 2*(gq&1);
        sB[dw]   = pk2(v0,v1);
        sB[dw+1] = pk2(v2,v3);
      }
    }
}

// ---------------------------------------------------------------------------
// K1: node encode + step-0 projections (A-frags on the fly), grid 239 x 384.
// Blocks 0..127: node work. Blocks 128..238: pk_e edge-weight packing riders.
// ---------------------------------------------------------------------------
__global__ __launch_bounds__(384)
void k1_node(const float* __restrict__ node_rep,
             const float* __restrict__ ne_W, const float* __restrict__ ne_b,
             const float* __restrict__ ee_W, const float* __restrict__ ee_b,
             const float* __restrict__ ep0_W1, const float* __restrict__ ep0_b1,
             const float* __restrict__ ep0_W2, const float* __restrict__ ep1_W1,
             const float* __restrict__ ep1_W2, const float* __restrict__ pred_W1,
             const float* __restrict__ pred_W2,
             unsigned* __restrict__ pk_e,
             float* __restrict__ wr_t, float* __restrict__ ws_t,
             float* __restrict__ ner0_t, float* __restrict__ nes0_t,
             float* __restrict__ enc_t)
{
    int blk = blockIdx.x, tid = threadIdx.x;
    if (blk >= 128) {                    // pk_e packing riders (64 threads used)
        if (tid < 64) {
            int t = blk - 128, l = tid;
            int cL = l & 15, gq = l >> 4;
            if (t < 108) {
                int mat = t/18, tt = t%18, mt = tt/3, kb = tt%3;
                const float* mats[6] = { ep0_W1 + 2*HH*HH, ep0_W2, ep1_W1 + 2*HH*HH,
                                         ep1_W2, pred_W1, pred_W1 + HH*HH };
                const float* src = mats[mat];
                u32x4 d;
                #pragma unroll
                for (int p=0;p<4;p++){
                    int k = 32*kb + 8*gq + 2*p;
                    d[p] = pk2(src[k*HH + 16*mt + cL], src[(k+1)*HH + 16*mt + cL]);
                }
                *(u32x4*)&pk_e[mat*4608 + (mt*3+kb)*256 + l*4] = d;
            } else {                     // pred_W2 zero-padded to 16 cols
                int kb = t - 108;
                u32x4 d;
                #pragma unroll
                for (int p=0;p<4;p++){
                    int k = 32*kb + 8*gq + 2*p;
                    float lo = (cL < 2) ? pred_W2[k*2 + cL]     : 0.f;
                    float hi = (cL < 2) ? pred_W2[(k+1)*2 + cL] : 0.f;
                    d[p] = pk2(lo, hi);
                }
                *(u32x4*)&pk_e[PE_P2 + kb*256 + l*4] = d;
            }
        }
        return;
    }

    int br = blk >> 2, chunk = blk & 3;
    int b = br >> 3, r = br & 7;
    int w = tid >> 6, l = tid & 63;
    int cL = l & 15, gq = l >> 4;
    int col = 16*chunk + cL;
    __shared__ float sN[DD*16];                    // node chunk [32 feats][16 cols]
    __shared__ __align__(16) float sF[HH*LSTR];    // repack buffer [96][17]
    size_t brb = (size_t)br * HH * NN;

    for (int idx = tid; idx < 512; idx += 384){
        int row = idx >> 5, k = idx & 31;
        sN[k*16 + row] = node_rep[((size_t)((b*NN + 16*chunk + row)*RR + r))*DD + k];
    }
    __syncthreads();

    u32x4 nBh, nBl;
    #pragma unroll
    for (int p=0;p<4;p++){
        int k = 8*gq + 2*p;
        unsigned h, lo;
        split2(sN[k*16 + cL], sN[(k+1)*16 + cL], h, lo);
        nBh[p] = h; nBl[p] = lo;
    }

    f32x4 acc;
    u32x4 Ah, Al;

    // enc = relu(node @ neW + ne_b)   (wave w -> m-tile w)
    cinit1(acc, ne_b, w, gq);
    buildA(ne_W, w, 0, gq, cL, Ah, Al);
    gemm_fly(acc, Ah, Al, nBh, nBl);
    relu1(acc);
    storeT1(acc, enc_t + brb, w, gq, col);
    toLds1(acc, sF, w, gq, cL);
    __syncthreads();

    // ner0 = enc @ Er0 + ep0_b1
    cinit1(acc, ep0_b1, w, gq);
    gemm96_fly(acc, ep0_W1, w, gq, cL, sF);
    storeT1(acc, ner0_t + brb, w, gq, col);

    // nes0 = enc @ Es0
    #pragma unroll
    for (int q=0;q<4;q++) acc[q] = 0.f;
    gemm96_fly(acc, ep0_W1 + HH*HH, w, gq, cL, sF);
    storeT1(acc, nes0_t + brb, w, gq, col);

    // wr' = node @ Wr + ee_b
    cinit1(acc, ee_b, w, gq);
    buildA(ee_W, w, 0, gq, cL, Ah, Al);
    gemm_fly(acc, Ah, Al, nBh, nBl);
    storeT1(acc, wr_t + brb, w, gq, col);

    // ws = node @ Ws
    #pragma unroll
    for (int q=0;q<4;q++) acc[q] = 0.f;
    buildA(ee_W + DD*HH, w, 0, gq, cL, Ah, Al);
    gemm_fly(acc, Ah, Al, nBh, nBl);
    storeT1(acc, ws_t + brb, w, gq, col);
}

// ---------------------------------------------------------------------------
// K2: edge prop step 0 via MFMA. block = 128 (2 waves, 3 m-tiles/wave).
// edge_enc B-frags built UPFRONT (all L2 loads issue early, overlap C-init);
// __launch_bounds__(128,4) pins VGPR<=128 -> 4 waves/SIMD, 8 blocks/CU.
// ---------------------------------------------------------------------------
__global__ __launch_bounds__(128, 4)
void k2_edge0(const float* __restrict__ wr_t, const float* __restrict__ ws_t,
              const float* __restrict__ ner0_t, const float* __restrict__ nes0_t,
              const unsigned* __restrict__ pk_e,
              const float* __restrict__ ep0_b2,
              unsigned* __restrict__ ee0f, float* __restrict__ agg_t)
{
    int g = blockIdx.x, tid = threadIdx.x;
    int w = tid >> 6, l = tid & 63;
    int b = g >> 9, r = g & 7, i = (g >> 3) & 63;
    int cL = l & 15, gq = l >> 4;
    int mBase = 3*w;
    size_t brb = (size_t)(b*RR + r)*HH*NN;
    const float* wrt = wr_t   + brb;
    const float* nrt = ner0_t + brb;
    const float* wst = ws_t   + brb;
    const float* nst = nes0_t + brb;
    __shared__ __align__(16) unsigned sB[3072];

    // build all edge_enc B-frags upfront — loads issue back-to-back
    u32x4 ee[3][4];
    #pragma unroll
    for (int kb=0;kb<3;kb++) build_ee_kb(ee[kb], wrt, wst, i, kb, gq, cL);

    f32x4 acc[3][4];
    #pragma unroll
    for (int mi=0;mi<3;mi++)
      #pragma unroll
      for (int q=0;q<4;q++){
        int c = 16*(mBase+mi) + 4*gq + q;
        float nr = nrt[c*NN + i];
        #pragma unroll
        for (int n=0;n<4;n++) acc[mi][n][q] = nr + nst[c*NN + 16*n + cL];
      }

    // GEMM1: t0 = Ee0^T @ edge_enc^T
    #pragma unroll
    for (int kb=0;kb<3;kb++)
        egemm_kb(acc, pk_e + PE_EE0, mBase, kb, l, ee[kb]);
    repack_half(acc, sB, mBase, gq, cL);
    __syncthreads();

    // GEMM2: ee0 = W20^T @ t0^T
    einit_b(acc, ep0_b2, mBase, gq);
    #pragma unroll
    for (int kb=0;kb<3;kb++){
        u32x4 Bk[4];
        load_sB_kb(Bk, sB, kb, l);
        egemm_kb(acc, pk_e + PE_W20, mBase, kb, l, Bk);
    }
    #pragma unroll
    for (int mi=0;mi<3;mi++)
      #pragma unroll
      for (int n=0;n<4;n++)
        #pragma unroll
        for (int q=0;q<4;q++) acc[mi][n][q] = fmaxf(acc[mi][n][q], 0.f);

    unsigned* eo = ee0f + (size_t)g*3072;
    #pragma unroll
    for (int mi=0;mi<3;mi++){
      int m = mBase+mi;
      #pragma unroll
      for (int n=0;n<4;n++){
        int gd = 2*(m&1) + (gq>>1);
        int dw = (((m>>1)*4 + n)*64 + 16*gd + cL)*4 + 2*(gq&1);
        eo[dw]   = pk2(acc[mi][n][0], acc[mi][n][1]);
        eo[dw+1] = pk2(acc[mi][n][2], acc[mi][n][3]);
      }
    }
    #pragma unroll
    for (int mi=0;mi<3;mi++)
      #pragma unroll
      for (int q=0;q<4;q++){
        float s = acc[mi][0][q] + acc[mi][1][q] + acc[mi][2][q] + acc[mi][3][q];
        s += __shfl_xor(s, 1);
        s += __shfl_xor(s, 2);
        s += __shfl_xor(s, 4);
        s += __shfl_xor(s, 8);
        if (cL == 0) agg_t[brb + (16*(mBase+mi) + 4*gq + q)*NN + i] = s;
      }
}

// ---------------------------------------------------------------------------
// K3: node update + step-1 projections (A-frags on the fly). grid 128 x 384.
// ---------------------------------------------------------------------------
__global__ __launch_bounds__(384)
void k3_node(const float* __restrict__ enc_t_g, const float* __restrict__ agg_t_g,
             const float* __restrict__ np_W1, const float* __restrict__ np_b1,
             const float* __restrict__ np_W2, const float* __restrict__ np_b2,
             const float* __restrict__ ep1_W1, const float* __restrict__ ep1_b1,
             float* __restrict__ ner1_t, float* __restrict__ nes1_t)
{
    int blk = blockIdx.x, tid = threadIdx.x;
    int br = blk >> 2, chunk = blk & 3;
    int w = tid >> 6, l = tid & 63;
    int cL = l & 15, gq = l >> 4;
    int col = 16*chunk + cL;
    __shared__ __align__(16) float sE[HH*LSTR], sA[HH*LSTR], sF[HH*LSTR];
    size_t brb = (size_t)br * HH * NN;
    const float* enc_t = enc_t_g + brb;
    const float* agg_t = agg_t_g + brb;

    for (int idx = tid; idx < HH*16; idx += 384){
        int f = idx >> 4, c = idx & 15;
        sE[f*LSTR + c] = enc_t[f*NN + 16*chunk + c];
        sA[f*LSTR + c] = agg_t[f*NN + 16*chunk + c];
    }
    __syncthreads();

    f32x4 acc;

    // t = relu(enc @ Wn12 + agg @ Wn3 + np_b1)
    cinit1(acc, np_b1, w, gq);
    gemm96_fly2(acc, np_W1, np_W1 + HH*HH, w, gq, cL, sE);   // Wn12 fold
    gemm96_fly(acc, np_W1 + 2*HH*HH, w, gq, cL, sA);         // Wn3
    relu1(acc);
    toLds1(acc, sF, w, gq, cL);
    __syncthreads();

    // ne1 = relu(t @ npW2 + np_b2)
    cinit1(acc, np_b2, w, gq);
    gemm96_fly(acc, np_W2, w, gq, cL, sF);
    relu1(acc);
    __syncthreads();                 // drain reads of t before overwrite
    toLds1(acc, sF, w, gq, cL);
    __syncthreads();

    // ner1 = ne1 @ Er1 + ep1_b1
    cinit1(acc, ep1_b1, w, gq);
    gemm96_fly(acc, ep1_W1, w, gq, cL, sF);
    storeT1(acc, ner1_t + brb, w, gq, col);

    // nes1 = ne1 @ Es1
    #pragma unroll
    for (int q=0;q<4;q++) acc[q] = 0.f;
    gemm96_fly(acc, ep1_W1 + HH*HH, w, gq, cL, sF);
    storeT1(acc, nes1_t + brb, w, gq, col);
}

// ---------------------------------------------------------------------------
// K4: edge prop step 1 + prediction head. block = 128 (2 waves, 3 m-tiles/wave).
// bf0 loaded upfront; GEMM4's edge_enc built before the drain barrier so its
// L2 loads overlap barrier convergence. __launch_bounds__(128,4).
// ---------------------------------------------------------------------------
__global__ __launch_bounds__(128, 4)
void k4_edge1(const float* __restrict__ wr_t, const float* __restrict__ ws_t,
              const float* __restrict__ ner1_t, const float* __restrict__ nes1_t,
              const unsigned* __restrict__ pk_e,
              const unsigned* __restrict__ ee0f,
              const float* __restrict__ ep1_b2,
              const float* __restrict__ pred_b1, const float* __restrict__ pred_b2,
              float* __restrict__ out)
{
    int g = blockIdx.x, tid = threadIdx.x;
    int w = tid >> 6, l = tid & 63;
    int b = g >> 9, i = (g >> 3) & 63, r = g & 7;
    int cL = l & 15, gq = l >> 4;
    int mBase = 3*w;
    size_t brb = (size_t)(b*RR + r)*HH*NN;
    const float* wrt = wr_t   + brb;
    const float* wst = ws_t   + brb;
    const float* nrt = ner1_t + brb;
    const float* nst = nes1_t + brb;
    __shared__ __align__(16) unsigned sB[3072];

    // load all ee0 B-frags upfront — 12 global loads issue back-to-back
    const u32x4* e0p = (const u32x4*)ee0f + (size_t)g*768;
    u32x4 bf0[3][4];
    #pragma unroll
    for (int kb=0;kb<3;kb++)
      #pragma unroll
      for (int n=0;n<4;n++) bf0[kb][n] = e0p[(kb*4+n)*64 + l];

    f32x4 acc[3][4];
    #pragma unroll
    for (int mi=0;mi<3;mi++)
      #pragma unroll
      for (int q=0;q<4;q++){
        int c = 16*(mBase+mi) + 4*gq + q;
        float nr = nrt[c*NN + i];
        #pragma unroll
        for (int n=0;n<4;n++) acc[mi][n][q] = nr + nst[c*NN + 16*n + cL];
      }

    // GEMM1: t1 = Ee1^T @ ee0^T
    #pragma unroll
    for (int kb=0;kb<3;kb++)
        egemm_kb(acc, pk_e + PE_EE1, mBase, kb, l, bf0[kb]);
    repack_half(acc, sB, mBase, gq, cL);         // t1 -> sB
    __syncthreads();

    // GEMM2: ee1 = W21^T @ t1^T
    einit_b(acc, ep1_b2, mBase, gq);
    #pragma unroll
    for (int kb=0;kb<3;kb++){
        u32x4 Bk[4];
        load_sB_kb(Bk, sB, kb, l);
        egemm_kb(acc, pk_e + PE_W21, mBase, kb, l, Bk);
    }
    __syncthreads();                             // drain t1 reads
    repack_half(acc, sB, mBase, gq, cL);         // ee1 -> sB
    __syncthreads();

    // GEMM3: tp = pred_b1 + Pe^T @ ee1^T
    einit_b(acc, pred_b1, mBase, gq);
    #pragma unroll
    for (int kb=0;kb<3;kb++){
        u32x4 Bk[4];
        load_sB_kb(Bk, sB, kb, l);
        egemm_kb(acc, pk_e + PE_PE, mBase, kb, l, Bk);
    }

    // GEMM4: tp += Pc^T @ edge_enc^T — build+MFMA per kb (loads overlap MFMA;
    // none of this touches sB, so it runs before the drain barrier)
    #pragma unroll
    for (int kb=0;kb<3;kb++){
        u32x4 Bk[4];
        build_ee_kb(Bk, wrt, wst, i, kb, gq, cL);
        egemm_kb(acc, pk_e + PE_PC, mBase, kb, l, Bk);
    }
    __syncthreads();                             // drain ee1 reads
    repack_half(acc, sB, mBase, gq, cL);         // tp -> sB
    __syncthreads();

    // GEMM5: out = P2^T @ tp^T (rows 0,1 valid); wave w handles n = 2w, 2w+1
    f32x4 c5[2];
    #pragma unroll
    for (int nn=0;nn<2;nn++){
        c5[nn][0] = (gq == 0) ? pred_b2[0] : 0.f;
        c5[nn][1] = (gq == 0) ? pred_b2[1] : 0.f;
        c5[nn][2] = 0.f; c5[nn][3] = 0.f;
    }
    #pragma unroll
    for (int kb=0;kb<3;kb++){
        bf16x8 A2 = __builtin_bit_cast(bf16x8, *(const u32x4*)&pk_e[PE_P2 + (kb*64 + l)*4]);
        #pragma unroll
        for (int nn=0;nn<2;nn++){
            int n = 2*w + nn;
            bf16x8 Bf = __builtin_bit_cast(bf16x8, *(const u32x4*)&sB[((kb*4+n)*64 + l)*4]);
            c5[nn] = MFMA16(A2, Bf, c5[nn]);
        }
    }
    if (gq == 0) {
        float2* o2 = (float2*)out;
        #pragma unroll
        for (int nn=0;nn<2;nn++){
            size_t j = 16*(2*w+nn) + cL;
            o2[(((size_t)(b*NN + i))*NN + j)*RR + r] = make_float2(c5[nn][0], c5[nn][1]);
        }
    }
}

// ---------------------------------------------------------------------------
extern "C" void kernel_launch(void* const* d_in, const int* in_sizes, int n_in,
                              void* d_out, int out_size, void* d_ws, size_t ws_size,
                              hipStream_t stream)
{
    const float* node_rep = (const float*)d_in[0];
    const float* ne_W    = (const float*)d_in[1];
    const float* ne_b    = (const float*)d_in[2];
    const float* ee_W    = (const float*)d_in[3];
    const float* ee_b    = (const float*)d_in[4];
    const float* np_W1   = (const float*)d_in[5];
    const float* np_b1   = (const float*)d_in[6];
    const float* np_W2   = (const float*)d_in[7];
    const float* np_b2   = (const float*)d_in[8];
    const float* ep0_W1  = (const float*)d_in[9];
    const float* ep0_b1  = (const float*)d_in[10];
    const float* ep0_W2  = (const float*)d_in[11];
    const float* ep0_b2  = (const float*)d_in[12];
    const float* ep1_W1  = (const float*)d_in[13];
    const float* ep1_b1  = (const float*)d_in[14];
    const float* ep1_W2  = (const float*)d_in[15];
    const float* ep1_b2  = (const float*)d_in[16];
    const float* pred_W1 = (const float*)d_in[17];
    const float* pred_b1 = (const float*)d_in[18];
    const float* pred_W2 = (const float*)d_in[19];
    const float* pred_b2 = (const float*)d_in[20];
    float* wsf = (float*)d_ws;
    float* out = (float*)d_out;

    float* wr_t   = wsf + OFF_WR_T;
    float* ws_t   = wsf + OFF_WS_T;
    float* ner0_t = wsf + OFF_NER0;
    float* nes0_t = wsf + OFF_NES0;
    float* ner1_t = wsf + OFF_NER1;
    float* nes1_t = wsf + OFF_NES1;
    float* enc_t  = wsf + OFF_ENCT;
    float* agg_t  = wsf + OFF_AGGT;
    unsigned* pk_e = (unsigned*)(wsf + OFF_PKE);
    unsigned* ee0f = (unsigned*)(wsf + OFF_EE0F);

    k1_node<<<239, 384, 0, stream>>>(node_rep, ne_W, ne_b, ee_W, ee_b,
                                     ep0_W1, ep0_b1,
                                     ep0_W2, ep1_W1, ep1_W2, pred_W1, pred_W2,
                                     pk_e,
                                     wr_t, ws_t, ner0_t, nes0_t, enc_t);

    k2_edge0<<<NGROUP, 128, 0, stream>>>(wr_t, ws_t, ner0_t, nes0_t, pk_e, ep0_b2,
                                         ee0f, agg_t);

    k3_node<<<128, 384, 0, stream>>>(enc_t, agg_t, np_W1, np_b1, np_W2, np_b2,
                                     ep1_W1, ep1_b1, ner1_t, nes1_t);

    k4_edge1<<<NGROUP, 128, 0, stream>>>(wr_t, ws_t, ner1_t, nes1_t, pk_e, ee0f,
                                         ep1_b2, pred_b1, pred_b2, out);
}